// Round 1
// baseline (148.144 us; speedup 1.0000x reference)
//
#include <hip/hip_runtime.h>
#include <math.h>

// ---------------------------------------------------------------------------
// Insight: the reference output is  gelu(rowmean(x@W^T - subtract) + logN) + x.
// rowmean(x@W^T) = (1/N) * dot(x[m,:], colsum(W)).  No GEMM needed.
// ---------------------------------------------------------------------------

// Kernel A: wsum[k] = sum_n W[n*K + k].  Split over row-chunks, atomicAdd.
__global__ __launch_bounds__(256) void colsum_kernel(
    const float* __restrict__ w, float* __restrict__ wsum,
    int N, int K, int rows_per_block) {
    const int K4 = K >> 2;
    const int col4 = blockIdx.x * blockDim.x + threadIdx.x;   // float4 col index
    if (col4 >= K4) return;
    const int row0 = blockIdx.y * rows_per_block;
    int row1 = row0 + rows_per_block;
    if (row1 > N) row1 = N;
    const float4* w4 = (const float4*)w;
    float4 acc = make_float4(0.f, 0.f, 0.f, 0.f);
    for (int n = row0; n < row1; ++n) {
        float4 v = w4[(size_t)n * K4 + col4];
        acc.x += v.x; acc.y += v.y; acc.z += v.z; acc.w += v.w;
    }
    float* dst = wsum + (size_t)col4 * 4;
    atomicAdd(dst + 0, acc.x);
    atomicAdd(dst + 1, acc.y);
    atomicAdd(dst + 2, acc.z);
    atomicAdd(dst + 3, acc.w);
}

// Kernel B: submean = mean(subtract).  One block.
__global__ __launch_bounds__(256) void submean_kernel(
    const float* __restrict__ s, float* __restrict__ outp, int N, float invN) {
    float acc = 0.f;
    for (int i = threadIdx.x; i < N; i += 256) acc += s[i];
    #pragma unroll
    for (int off = 32; off > 0; off >>= 1) acc += __shfl_down(acc, off, 64);
    __shared__ float sd[4];
    if ((threadIdx.x & 63) == 0) sd[threadIdx.x >> 6] = acc;
    __syncthreads();
    if (threadIdx.x == 0) outp[0] = (sd[0] + sd[1] + sd[2] + sd[3]) * invN;
}

// Kernel C: one block per row.  dot(x_row, wsum) -> scalar gelu -> out = g + x.
// Assumes K == N == 4096 (block 256 threads * 4 float4 = 4096 elements).
__global__ __launch_bounds__(256) void fused_row_kernel(
    const float* __restrict__ x, const float* __restrict__ wsum,
    const float* __restrict__ submean_p, float* __restrict__ out,
    int K, float logN, float invN) {
    const int row = blockIdx.x;
    const int K4 = K >> 2;                       // 1024
    const float4* x4 = (const float4*)(x + (size_t)row * K);
    const float4* ws4 = (const float4*)wsum;

    float4 xv[4];
    float dot = 0.f;
    #pragma unroll
    for (int j = 0; j < 4; ++j) {
        const int idx = j * 256 + threadIdx.x;   // coalesced, idx < K4
        float4 xx = x4[idx];
        float4 ww = ws4[idx];
        xv[j] = xx;
        dot += xx.x * ww.x + xx.y * ww.y + xx.z * ww.z + xx.w * ww.w;
    }
    (void)K4;

    // 64-lane wave reduce, then across the block's 4 waves via LDS.
    #pragma unroll
    for (int off = 32; off > 0; off >>= 1) dot += __shfl_down(dot, off, 64);
    __shared__ float sd[4];
    if ((threadIdx.x & 63) == 0) sd[threadIdx.x >> 6] = dot;
    __syncthreads();
    const float total = sd[0] + sd[1] + sd[2] + sd[3];

    const float c = total * invN - submean_p[0] + logN;
    const float t = 0.7978845608028654f * (c + 0.044715f * c * c * c);
    const float g = 0.5f * c * (1.f + t / (fabsf(t) + 1.f));

    float4* o4 = (float4*)(out + (size_t)row * K);
    #pragma unroll
    for (int j = 0; j < 4; ++j) {
        const int idx = j * 256 + threadIdx.x;
        float4 xx = xv[j];
        xx.x += g; xx.y += g; xx.z += g; xx.w += g;
        o4[idx] = xx;
    }
}

extern "C" void kernel_launch(void* const* d_in, const int* in_sizes, int n_in,
                              void* d_out, int out_size, void* d_ws, size_t ws_size,
                              hipStream_t stream) {
    const float* x   = (const float*)d_in[0];
    const float* w   = (const float*)d_in[1];
    const float* sub = (const float*)d_in[2];
    float* out = (float*)d_out;

    const int N = in_sizes[2];            // 4096
    const int K = in_sizes[1] / N;        // 4096
    const int M = in_sizes[0] / K;        // 16384

    float* wsum    = (float*)d_ws;        // K floats
    float* submean = wsum + K;            // 1 float

    hipMemsetAsync(d_ws, 0, (size_t)(K + 1) * sizeof(float), stream);

    const int K4 = K / 4;
    const int rows_per_block = 64;
    dim3 gA((K4 + 255) / 256, (N + rows_per_block - 1) / rows_per_block);
    colsum_kernel<<<gA, 256, 0, stream>>>(w, wsum, N, K, rows_per_block);

    submean_kernel<<<1, 256, 0, stream>>>(sub, submean, N, 1.0f / (float)N);

    fused_row_kernel<<<M, 256, 0, stream>>>(x, wsum, submean, out,
                                            K, logf((float)N), 1.0f / (float)N);
}

// Round 3
// 131.482 us; speedup vs baseline: 1.1267x; 1.1267x over previous
//
#include <hip/hip_runtime.h>
#include <math.h>

// out = gelu(rowmean(x@W^T - subtract) + logN) + x
// rowmean(x@W^T)[m] = (1/N) * dot(x[m,:], colsum(W)).  No GEMM needed.

typedef float f4 __attribute__((ext_vector_type(4)));  // native vec for nontemporal builtins

// Kernel A: wsum[k] = sum_n W[n,k] (atomics over row-chunks).
// Last grid.y slice (blockIdx.x==0) also computes submean = mean(subtract).
__global__ __launch_bounds__(256) void colsum_kernel(
    const float* __restrict__ w, const float* __restrict__ sub,
    float* __restrict__ wsum, float* __restrict__ submean,
    int N, int K, int rows_per_block, float invN) {
    if (blockIdx.y == gridDim.y - 1) {
        if (blockIdx.x != 0) return;
        float acc = 0.f;
        for (int i = threadIdx.x; i < N; i += 256) acc += sub[i];
        #pragma unroll
        for (int off = 32; off > 0; off >>= 1) acc += __shfl_down(acc, off, 64);
        __shared__ float sd[4];
        if ((threadIdx.x & 63) == 0) sd[threadIdx.x >> 6] = acc;
        __syncthreads();
        if (threadIdx.x == 0) submean[0] = (sd[0] + sd[1] + sd[2] + sd[3]) * invN;
        return;
    }
    const int K4 = K >> 2;
    const int col4 = blockIdx.x * blockDim.x + threadIdx.x;
    if (col4 >= K4) return;
    const int row0 = blockIdx.y * rows_per_block;
    int row1 = row0 + rows_per_block;
    if (row1 > N) row1 = N;
    const f4* w4 = (const f4*)w;
    f4 acc = (f4)(0.f);
    for (int n = row0; n < row1; ++n) {
        acc += __builtin_nontemporal_load(&w4[(size_t)n * K4 + col4]);
    }
    float* dst = wsum + (size_t)col4 * 4;
    atomicAdd(dst + 0, acc.x);
    atomicAdd(dst + 1, acc.y);
    atomicAdd(dst + 2, acc.z);
    atomicAdd(dst + 3, acc.w);
}

// Kernel B: one WAVE per row (4 rows per 256-thread block).
// Lane holds 16 float4 of x in registers (1/64 of the row), dots against
// wsum, 6-step shuffle reduce (no LDS, no barriers), scalar gelu, store x+g.
__global__ __launch_bounds__(256) void fused_row_kernel(
    const float* __restrict__ x, const float* __restrict__ wsum,
    const float* __restrict__ submean_p, float* __restrict__ out,
    int M, int K, float logN, float invN) {
    const int lane = threadIdx.x & 63;
    const int row = blockIdx.x * 4 + (threadIdx.x >> 6);
    if (row >= M) return;
    const f4* x4 = (const f4*)(x + (size_t)row * K);
    const f4* ws4 = (const f4*)wsum;

    f4 xv[16];
    float dot = 0.f;
    #pragma unroll
    for (int j = 0; j < 16; ++j) {
        const int idx = j * 64 + lane;               // coalesced per wave
        const f4 xx = __builtin_nontemporal_load(&x4[idx]);
        const f4 ww = ws4[idx];                      // L2/L1-resident (16 KB)
        xv[j] = xx;
        dot = fmaf(xx.x, ww.x, fmaf(xx.y, ww.y,
              fmaf(xx.z, ww.z, fmaf(xx.w, ww.w, dot))));
    }

    #pragma unroll
    for (int off = 1; off < 64; off <<= 1) dot += __shfl_xor(dot, off, 64);

    const float c = dot * invN - submean_p[0] + logN;
    const float t = 0.7978845608028654f * fmaf(0.044715f * c, c * c, c);
    const float g = 0.5f * c * (1.f + t / (fabsf(t) + 1.f));

    f4* o4 = (f4*)(out + (size_t)row * K);
    #pragma unroll
    for (int j = 0; j < 16; ++j) {
        const int idx = j * 64 + lane;
        f4 v = xv[j] + (f4)(g);
        __builtin_nontemporal_store(v, &o4[idx]);
    }
}

extern "C" void kernel_launch(void* const* d_in, const int* in_sizes, int n_in,
                              void* d_out, int out_size, void* d_ws, size_t ws_size,
                              hipStream_t stream) {
    const float* x   = (const float*)d_in[0];
    const float* w   = (const float*)d_in[1];
    const float* sub = (const float*)d_in[2];
    float* out = (float*)d_out;

    const int N = in_sizes[2];            // 4096
    const int K = in_sizes[1] / N;        // 4096
    const int M = in_sizes[0] / K;        // 16384

    float* wsum    = (float*)d_ws;        // K floats
    float* submean = wsum + K;            // 1 float

    (void)hipMemsetAsync(d_ws, 0, (size_t)(K + 1) * sizeof(float), stream);

    const int K4 = K / 4;
    const int rows_per_block = 64;
    dim3 gA((K4 + 255) / 256, N / rows_per_block + 1);
    colsum_kernel<<<gA, 256, 0, stream>>>(w, sub, wsum, submean,
                                          N, K, rows_per_block, 1.0f / (float)N);

    fused_row_kernel<<<(M + 3) / 4, 256, 0, stream>>>(
        x, wsum, submean, out, M, K, logf((float)N), 1.0f / (float)N);
}